// Round 1
// baseline (353.052 us; speedup 1.0000x reference)
//
#include <hip/hip_runtime.h>
#include <stdint.h>

// B=32, C=256, P=2 pods, 64x64 spatial (pos=4096). f32 I/O, bf16 MFMA inside.
// R6: k_gemm rewritten — direct-to-LDS B staging (global_load_lds dwordx4,
//   transposed-linear [ch][r] LDS layout matching F's global layout, so no
//   swizzle anywhere), B double-buffered, A+B prefetch issued before the MFMA
//   phase so global latency hides under compute. MFMA sequence/order identical
//   to R5 -> bit-identical f6. k_fwd / k_inv byte-identical to R5 (clean A/B).
// d_out slot map (16 KiB per img): lo 8 KiB = f6, hi 8 KiB = F via Faddr().

typedef __attribute__((ext_vector_type(4))) float f32x4_t;
typedef __attribute__((ext_vector_type(8))) __bf16 bf16x8_t;
typedef __attribute__((ext_vector_type(8))) unsigned short u16x8_t;
typedef __attribute__((ext_vector_type(4))) unsigned short u16x4_t;

__device__ __forceinline__ float bf2f(unsigned short u) {
  union { unsigned int i; float f; } x; x.i = ((unsigned int)u) << 16; return x.f;
}
__device__ __forceinline__ unsigned short f2bf(float f) {   // RNE
  union { float f; unsigned int i; } x; x.f = f;
  unsigned int i = x.i;
  return (unsigned short)((i + 0x7FFFu + ((i >> 16) & 1u)) >> 16);
}
__device__ __forceinline__ unsigned short f2bf_t(float f) { // truncate (staging)
  union { float f; unsigned int i; } x; x.f = f;
  return (unsigned short)(x.i >> 16);
}
// linear u16 index into F -> physical u16 offset in d_out (slot upper halves)
__device__ __forceinline__ size_t Faddr(size_t f) {
  return ((f >> 12) << 13) + 4096 + (f & 4095);
}

// ---------------- k_fwd: 2D WHT via MFMA, write F tiled (unchanged R5) ----------------
// block = 512 thr = 8 waves, wave -> image c = cg*8+wave; grid (32 cg, 32 b)
__global__ __launch_bounds__(512) void k_fwd(const float* __restrict__ x,
                                             unsigned short* __restrict__ obuf) {
  __shared__ unsigned short smem[36864];       // 72 KiB: 8x T1t(4608) / Fbuf overlay
  int tid = threadIdx.x;
  int lane = tid & 63, wave = tid >> 6;
  int quad = lane >> 4, l15 = lane & 15;
  int cg = blockIdx.x, b = blockIdx.y;
  size_t img = (size_t)b * 256 + cg * 8 + wave;
  unsigned short* T1t = smem + wave * 4608;    // per-wave [64][72] u16 tile

  // stage X coalesced: flat float4 -> bf16 tile [h][w] (stride 72)
  const float* xim = x + img * 4096;
#pragma unroll
  for (int l = 0; l < 16; l++) {
    int e = (l * 64 + lane) * 4;
    f32x4_t sv = *(const f32x4_t*)(xim + e);
    u16x4_t u;
#pragma unroll
    for (int j = 0; j < 4; j++) u[j] = f2bf_t(sv[j]);
    int row = e >> 6, col = e & 63;
    *(u16x4_t*)&T1t[row * 72 + col] = u;
  }

  // H fragments: hf[kc][t][j] = sign(parity((kc*32+quad*8+j) & (t*16+l15)))
  bf16x8_t hf[2][4];
#pragma unroll
  for (int kc = 0; kc < 2; kc++)
#pragma unroll
    for (int t = 0; t < 4; t++) {
      bf16x8_t h;
#pragma unroll
      for (int j = 0; j < 8; j++) {
        int k = kc * 32 + quad * 8 + j, n = t * 16 + l15;
        h[j] = (__builtin_popcount(k & n) & 1) ? (__bf16)-1.0f : (__bf16)1.0f;
      }
      hf[kc][t] = h;
    }

  // X A-fragments from LDS (b128, same-wave ordering after staging writes)
  bf16x8_t xa[4][2];
#pragma unroll
  for (int mt = 0; mt < 4; mt++)
#pragma unroll
    for (int kc = 0; kc < 2; kc++)
      xa[mt][kc] = *(const bf16x8_t*)&T1t[(mt * 16 + l15) * 72 + kc * 32 + quad * 8];

  // GEMM1: T1 = X*H, strip-mined by nt; store transposed [kw][h] into T1t
#pragma unroll
  for (int nt = 0; nt < 4; nt++) {
    f32x4_t a1c[4];
#pragma unroll
    for (int mt = 0; mt < 4; mt++) a1c[mt] = (f32x4_t){0.f, 0.f, 0.f, 0.f};
#pragma unroll
    for (int kc = 0; kc < 2; kc++)
#pragma unroll
      for (int mt = 0; mt < 4; mt++)
        a1c[mt] = __builtin_amdgcn_mfma_f32_16x16x32_bf16(xa[mt][kc], hf[kc][nt], a1c[mt], 0, 0, 0);
#pragma unroll
    for (int mt = 0; mt < 4; mt++) {
      u16x4_t t4;
#pragma unroll
      for (int r = 0; r < 4; r++) t4[r] = f2bf_t(a1c[mt][r]);
      *(u16x4_t*)&T1t[(nt * 16 + l15) * 72 + mt * 16 + quad * 4] = t4;
    }
  }

  // GEMM2: f2 = H*T1
  f32x4_t acc[4][4];
#pragma unroll
  for (int mt = 0; mt < 4; mt++)
#pragma unroll
    for (int nt = 0; nt < 4; nt++) acc[mt][nt] = (f32x4_t){0.f, 0.f, 0.f, 0.f};
#pragma unroll
  for (int kc = 0; kc < 2; kc++)
#pragma unroll
    for (int nt = 0; nt < 4; nt++) {
      bf16x8_t bfr = *(bf16x8_t*)&T1t[(nt * 16 + l15) * 72 + kc * 32 + quad * 8];
#pragma unroll
      for (int mt = 0; mt < 4; mt++)
        acc[mt][nt] = __builtin_amdgcn_mfma_f32_16x16x32_bf16(hf[kc][mt], bfr, acc[mt][nt], 0, 0, 0);
    }

  __syncthreads();                             // all T1t reads done before overlay
  // fill Fbuf[pos][c8]: this wave supplies c-lane = wave
#pragma unroll
  for (int mt = 0; mt < 4; mt++)
#pragma unroll
    for (int nt = 0; nt < 4; nt++)
#pragma unroll
      for (int r = 0; r < 4; r++) {
        int pos = (mt * 16 + quad * 4 + r) * 64 + nt * 16 + l15;  // kh*64+kw
        smem[pos * 8 + wave] = f2bf(acc[mt][nt][r]);
      }
  __syncthreads();
  // drain: coalesced u16x8 stores to F via Faddr
  size_t fbase = ((size_t)b * 32 + cg) * 4096;
#pragma unroll
  for (int i = 0; i < 8; i++) {
    int pos = i * 512 + tid;
    u16x8_t vch = *(u16x8_t*)&smem[pos * 8];
    *(u16x8_t*)(obuf + Faddr((fbase + pos) * 8)) = vch;
  }
}

// ---------------- k_gemm: Wcat @ F + soft-threshold (R6 pipeline) ----------------
// block = 256 thr = 4 waves; grid (32 n-tile, 4 m-tile, 32 b)
// LDS: Alds [8 ch][128 m] 16B chunks (16 KiB) @0; Blds double [2][8 ch][128 r] @8192.
// B goes global_load_lds dwordx4 straight from F (layout already linear in
// (cch,r) load order). A reg-staged f32->bf16. Prefetch ks+1 before MFMA(ks).
__global__ __launch_bounds__(256) void k_gemm(const float* __restrict__ Wf,
                                              const float* __restrict__ vv,
                                              const float* __restrict__ TT,
                                              unsigned short* __restrict__ obuf) {
  __shared__ unsigned short smem2[24576];      // 48 KiB; epilogue overlays [0..8704)
  unsigned short* Alds = smem2;
  int tid = threadIdx.x;
  int lane = tid & 63, wave = tid >> 6;
  int quad = lane >> 4, l15 = lane & 15;
  int wm = wave & 1, wn = wave >> 1;
  int n0 = blockIdx.x * 128;                   // pos tile
  int m0 = blockIdx.y * 128;                   // Wcat row tile (m=2o+p)
  int b  = blockIdx.z;

  f32x4_t acc[4][4];
#pragma unroll
  for (int mt = 0; mt < 4; mt++)
#pragma unroll
    for (int nt = 0; nt < 4; nt++) acc[mt][nt] = (f32x4_t){0.f, 0.f, 0.f, 0.f};

  // ---- staging helpers ----
  auto issueB = [&](int ks, int buf) {         // 4x global_load_lds dwordx4
    unsigned short* Bl = smem2 + 8192 + buf * 8192;
#pragma unroll
    for (int i = 0; i < 4; i++) {
      int idx = i * 256 + tid;
      int r = idx & 127, cch = idx >> 7;
      size_t f = (((size_t)b * 32 + ks * 8 + cch) * 4096 + n0 + r) * 8;
      const unsigned short* src = obuf + Faddr(f);
      __builtin_amdgcn_global_load_lds(
          (const __attribute__((address_space(1))) void*)src,
          (__attribute__((address_space(3))) void*)(Bl + idx * 8), 16, 0, 0);
    }
  };
  auto loadA = [&](int ks, f32x4_t (&ar)[4][2]) {
    int k0 = ks * 64;
#pragma unroll
    for (int i = 0; i < 4; i++) {
      int idx = i * 256 + tid;
      int r = idx >> 3, cch = idx & 7;
      int m = m0 + r;
      const float* wp = Wf + ((m & 1) << 16) + ((m >> 1) << 8) + k0 + cch * 8;
      ar[i][0] = *(const f32x4_t*)wp;
      ar[i][1] = *(const f32x4_t*)(wp + 4);
    }
  };
  auto writeA = [&](f32x4_t (&ar)[4][2]) {     // convert + linear [ch][m] store
#pragma unroll
    for (int i = 0; i < 4; i++) {
      int idx = i * 256 + tid;
      int r = idx >> 3, cch = idx & 7;
      u16x8_t u;
#pragma unroll
      for (int j = 0; j < 4; j++) { u[j] = f2bf_t(ar[i][0][j]); u[4 + j] = f2bf_t(ar[i][1][j]); }
      *(u16x8_t*)&Alds[cch * 1024 + r * 8] = u;
    }
  };

  f32x4_t areg[4][2];
  issueB(0, 0);                                // B(0) in flight during A(0) stage
  loadA(0, areg);
  writeA(areg);
  __syncthreads();                             // drains vmcnt(0)+lgkm: B(0)+A(0) ready

  int kbuf = 0;
  for (int ks = 0; ks < 4; ++ks) {
    if (ks < 3) {                              // prefetch next tile before compute
      issueB(ks + 1, kbuf ^ 1);
      loadA(ks + 1, areg);
    }
    unsigned short* Bl = smem2 + 8192 + kbuf * 8192;
#pragma unroll
    for (int kk = 0; kk < 2; ++kk) {
      int ch = kk * 4 + quad;
      bf16x8_t af[4], bfr[4];
#pragma unroll
      for (int mt = 0; mt < 4; mt++)
        af[mt] = *(const bf16x8_t*)&Alds[ch * 1024 + (wm * 64 + mt * 16 + l15) * 8];
#pragma unroll
      for (int nt = 0; nt < 4; nt++)
        bfr[nt] = *(const bf16x8_t*)&Bl[ch * 1024 + (wn * 64 + nt * 16 + l15) * 8];
#pragma unroll
      for (int mt = 0; mt < 4; mt++)
#pragma unroll
        for (int nt = 0; nt < 4; nt++)
          acc[mt][nt] = __builtin_amdgcn_mfma_f32_16x16x32_bf16(af[mt], bfr[nt], acc[mt][nt], 0, 0, 0);
    }
    __syncthreads();                           // reads(cur) done; drain lands B(ks+1)
    if (ks < 3) {
      writeA(areg);                            // Alds overwrite now safe
      __syncthreads();                         // A(ks+1) visible to all waves
    }
    kbuf ^= 1;
  }

  // epilogue: v-scale + soft-threshold both pods (reg parity = pod)
  // -> LDS tile [64 o][136 pos-stride] -> coalesced f6 row stores (slot-lo)
#pragma unroll
  for (int nt = 0; nt < 4; nt++) {
    int posl = wn * 64 + nt * 16 + l15;
    int pos = n0 + posl;
    float v0 = vv[pos], v1 = vv[4096 + pos];
    float t0 = TT[pos], t1 = TT[4096 + pos];
#pragma unroll
    for (int mt = 0; mt < 4; mt++)
#pragma unroll
      for (int rp = 0; rp < 2; rp++) {
        int ol = wm * 32 + mt * 8 + quad * 2 + rp;
        float z0 = acc[mt][nt][rp * 2 + 0] * v0;
        float z1 = acc[mt][nt][rp * 2 + 1] * v1;
        float s0 = copysignf(fmaxf(fabsf(z0) - t0, 0.f), z0);
        float s1 = copysignf(fmaxf(fabsf(z1) - t1, 0.f), z1);
        smem2[ol * 136 + posl] = f2bf(s0 + s1);
      }
  }
  __syncthreads();
  int o0 = m0 >> 1;
#pragma unroll
  for (int i = 0; i < 4; i++) {
    int ci = i * 256 + tid;                    // 1024 chunks = 64 rows x 16
    int row = ci >> 4, cc = ci & 15;
    u16x8_t vch = *(u16x8_t*)&smem2[row * 136 + cc * 8];
    size_t img = (size_t)b * 256 + o0 + row;
    *(u16x8_t*)(obuf + img * 8192 + n0 + cc * 8) = vch;
  }
}

// ---------------- k_inv: inverse 2D WHT via MFMA + /4096 + x (unchanged R5) ----------------
// block = 256 thr = 4 waves, wave -> image; grid 2048
__global__ __launch_bounds__(256) void k_inv(const float* __restrict__ x,
                                             unsigned short* __restrict__ obuf) {
  __shared__ unsigned short smem[18432];       // 4x per-wave [64][72] u16 tile
  int tid = threadIdx.x;
  int lane = tid & 63, wave = tid >> 6;
  int quad = lane >> 4, l15 = lane & 15;
  size_t img = (size_t)blockIdx.x * 4 + wave;
  unsigned short* T1t = smem + wave * 4608;

  // stage f6 coalesced (slot-lo u16x8) -> LDS tile [h][w] stride 72
#pragma unroll
  for (int l = 0; l < 8; l++) {
    int e = (l * 64 + lane) * 8;
    u16x8_t sv = *(const u16x8_t*)(obuf + img * 8192 + e);
    int row = e >> 6, col = e & 63;
    *(u16x8_t*)&T1t[row * 72 + col] = sv;
  }

  bf16x8_t hf[2][4];
#pragma unroll
  for (int kc = 0; kc < 2; kc++)
#pragma unroll
    for (int t = 0; t < 4; t++) {
      bf16x8_t h;
#pragma unroll
      for (int j = 0; j < 8; j++) {
        int k = kc * 32 + quad * 8 + j, n = t * 16 + l15;
        h[j] = (__builtin_popcount(k & n) & 1) ? (__bf16)-1.0f : (__bf16)1.0f;
      }
      hf[kc][t] = h;
    }

  // A-frags from LDS
  bf16x8_t fa[4][2];
#pragma unroll
  for (int mt = 0; mt < 4; mt++)
#pragma unroll
    for (int kc = 0; kc < 2; kc++)
      fa[mt][kc] = *(const bf16x8_t*)&T1t[(mt * 16 + l15) * 72 + kc * 32 + quad * 8];

  // GEMM1: U = f6*H, strip-mined; store transposed into T1t (reuse)
#pragma unroll
  for (int nt = 0; nt < 4; nt++) {
    f32x4_t a1c[4];
#pragma unroll
    for (int mt = 0; mt < 4; mt++) a1c[mt] = (f32x4_t){0.f, 0.f, 0.f, 0.f};
#pragma unroll
    for (int kc = 0; kc < 2; kc++)
#pragma unroll
      for (int mt = 0; mt < 4; mt++)
        a1c[mt] = __builtin_amdgcn_mfma_f32_16x16x32_bf16(fa[mt][kc], hf[kc][nt], a1c[mt], 0, 0, 0);
#pragma unroll
    for (int mt = 0; mt < 4; mt++) {
      u16x4_t t4;
#pragma unroll
      for (int r = 0; r < 4; r++) t4[r] = f2bf_t(a1c[mt][r]);
      *(u16x4_t*)&T1t[(nt * 16 + l15) * 72 + mt * 16 + quad * 4] = t4;
    }
  }

  // GEMM2: V = H*U
  f32x4_t acc[4][4];
#pragma unroll
  for (int mt = 0; mt < 4; mt++)
#pragma unroll
    for (int nt = 0; nt < 4; nt++) acc[mt][nt] = (f32x4_t){0.f, 0.f, 0.f, 0.f};
#pragma unroll
  for (int kc = 0; kc < 2; kc++)
#pragma unroll
    for (int nt = 0; nt < 4; nt++) {
      bf16x8_t bfr = *(bf16x8_t*)&T1t[(nt * 16 + l15) * 72 + kc * 32 + quad * 8];
#pragma unroll
      for (int mt = 0; mt < 4; mt++)
        acc[mt][nt] = __builtin_amdgcn_mfma_f32_16x16x32_bf16(hf[kc][mt], bfr, acc[mt][nt], 0, 0, 0);
    }

  // acc -> LDS tile [hh][ww] as bf16*(1/4096) (scalar u16 writes, 2-way free)
  const float sc = 1.0f / 4096.0f;
#pragma unroll
  for (int mt = 0; mt < 4; mt++)
#pragma unroll
    for (int nt = 0; nt < 4; nt++)
#pragma unroll
      for (int r = 0; r < 4; r++)
        T1t[(mt * 16 + quad * 4 + r) * 72 + nt * 16 + l15] = f2bf(acc[mt][nt][r] * sc);

  // drain: coalesced — LDS row chunks + x residual -> f32 out (in-place slot)
  float* outf = (float*)obuf;
  const float* xim = x + img * 4096;
#pragma unroll
  for (int l = 0; l < 8; l++) {
    int e = (l * 64 + lane) * 8;
    int row = e >> 6, col = e & 63;
    u16x8_t tv = *(u16x8_t*)&T1t[row * 72 + col];
    f32x4_t x0 = *(const f32x4_t*)(xim + e);
    f32x4_t x1 = *(const f32x4_t*)(xim + e + 4);
    f32x4_t o0, o1;
#pragma unroll
    for (int j = 0; j < 4; j++) { o0[j] = bf2f(tv[j]) + x0[j]; o1[j] = bf2f(tv[4 + j]) + x1[j]; }
    *(f32x4_t*)(outf + img * 4096 + e) = o0;
    *(f32x4_t*)(outf + img * 4096 + e + 4) = o1;
  }
}

extern "C" void kernel_launch(void* const* d_in, const int* in_sizes, int n_in,
                              void* d_out, int out_size, void* d_ws, size_t ws_size,
                              hipStream_t stream) {
  const float* x = (const float*)d_in[0];      // (32,256,64,64) f32
  const float* v = (const float*)d_in[1];      // (2,64,64) f32
  const float* W = (const float*)d_in[2];      // (2,256,256) f32
  const float* T = (const float*)d_in[3];      // (2,64,64) f32
  unsigned short* obuf = (unsigned short*)d_out;
  (void)d_ws; (void)ws_size; (void)in_sizes; (void)n_in; (void)out_size;

  k_fwd<<<dim3(32, 32), 512, 0, stream>>>(x, obuf);
  k_gemm<<<dim3(32, 4, 32), 256, 0, stream>>>(W, v, T, obuf);
  k_inv<<<2048, 256, 0, stream>>>(x, obuf);
}

// Round 2
// 333.500 us; speedup vs baseline: 1.0586x; 1.0586x over previous
//
#include <hip/hip_runtime.h>
#include <stdint.h>

// B=32, C=256, P=2 pods, 64x64 spatial (pos=4096). f32 I/O, bf16 MFMA inside.
// R7 k_gemm: hybrid of R5/R6 keeping only counter-proven-good paths.
//   B: global_load_lds dwordx4, linear [cch][r] LDS dest (R6: 0 write instrs,
//      0 read conflicts per PMC), double-buffered, issued before MFMA phase.
//   A: R5 path (gch=cch^(r&7) pre-swizzled coalesced fetch, LINEAR ds_write
//      -> conflict-free, XOR-swizzled read) + reg prefetch 1 ks ahead, dbuf.
//   One barrier per ks. R6's writeA was an 8-way bank conflict (1.49e7 extra
//   cycles == measured counter); eliminated here.
// k_fwd / k_inv byte-identical to R5 (clean A/B attribution).
// d_out slot map (16 KiB per img): lo 8 KiB = f6, hi 8 KiB = F via Faddr().

typedef __attribute__((ext_vector_type(4))) float f32x4_t;
typedef __attribute__((ext_vector_type(8))) __bf16 bf16x8_t;
typedef __attribute__((ext_vector_type(8))) unsigned short u16x8_t;
typedef __attribute__((ext_vector_type(4))) unsigned short u16x4_t;

__device__ __forceinline__ float bf2f(unsigned short u) {
  union { unsigned int i; float f; } x; x.i = ((unsigned int)u) << 16; return x.f;
}
__device__ __forceinline__ unsigned short f2bf(float f) {   // RNE
  union { float f; unsigned int i; } x; x.f = f;
  unsigned int i = x.i;
  return (unsigned short)((i + 0x7FFFu + ((i >> 16) & 1u)) >> 16);
}
__device__ __forceinline__ unsigned short f2bf_t(float f) { // truncate (staging)
  union { float f; unsigned int i; } x; x.f = f;
  return (unsigned short)(x.i >> 16);
}
// linear u16 index into F -> physical u16 offset in d_out (slot upper halves)
__device__ __forceinline__ size_t Faddr(size_t f) {
  return ((f >> 12) << 13) + 4096 + (f & 4095);
}

// ---------------- k_fwd: 2D WHT via MFMA, write F tiled (unchanged R5) ----------------
// block = 512 thr = 8 waves, wave -> image c = cg*8+wave; grid (32 cg, 32 b)
__global__ __launch_bounds__(512) void k_fwd(const float* __restrict__ x,
                                             unsigned short* __restrict__ obuf) {
  __shared__ unsigned short smem[36864];       // 72 KiB: 8x T1t(4608) / Fbuf overlay
  int tid = threadIdx.x;
  int lane = tid & 63, wave = tid >> 6;
  int quad = lane >> 4, l15 = lane & 15;
  int cg = blockIdx.x, b = blockIdx.y;
  size_t img = (size_t)b * 256 + cg * 8 + wave;
  unsigned short* T1t = smem + wave * 4608;    // per-wave [64][72] u16 tile

  // stage X coalesced: flat float4 -> bf16 tile [h][w] (stride 72)
  const float* xim = x + img * 4096;
#pragma unroll
  for (int l = 0; l < 16; l++) {
    int e = (l * 64 + lane) * 4;
    f32x4_t sv = *(const f32x4_t*)(xim + e);
    u16x4_t u;
#pragma unroll
    for (int j = 0; j < 4; j++) u[j] = f2bf_t(sv[j]);
    int row = e >> 6, col = e & 63;
    *(u16x4_t*)&T1t[row * 72 + col] = u;
  }

  // H fragments: hf[kc][t][j] = sign(parity((kc*32+quad*8+j) & (t*16+l15)))
  bf16x8_t hf[2][4];
#pragma unroll
  for (int kc = 0; kc < 2; kc++)
#pragma unroll
    for (int t = 0; t < 4; t++) {
      bf16x8_t h;
#pragma unroll
      for (int j = 0; j < 8; j++) {
        int k = kc * 32 + quad * 8 + j, n = t * 16 + l15;
        h[j] = (__builtin_popcount(k & n) & 1) ? (__bf16)-1.0f : (__bf16)1.0f;
      }
      hf[kc][t] = h;
    }

  // X A-fragments from LDS (b128, same-wave ordering after staging writes)
  bf16x8_t xa[4][2];
#pragma unroll
  for (int mt = 0; mt < 4; mt++)
#pragma unroll
    for (int kc = 0; kc < 2; kc++)
      xa[mt][kc] = *(const bf16x8_t*)&T1t[(mt * 16 + l15) * 72 + kc * 32 + quad * 8];

  // GEMM1: T1 = X*H, strip-mined by nt; store transposed [kw][h] into T1t
#pragma unroll
  for (int nt = 0; nt < 4; nt++) {
    f32x4_t a1c[4];
#pragma unroll
    for (int mt = 0; mt < 4; mt++) a1c[mt] = (f32x4_t){0.f, 0.f, 0.f, 0.f};
#pragma unroll
    for (int kc = 0; kc < 2; kc++)
#pragma unroll
      for (int mt = 0; mt < 4; mt++)
        a1c[mt] = __builtin_amdgcn_mfma_f32_16x16x32_bf16(xa[mt][kc], hf[kc][nt], a1c[mt], 0, 0, 0);
#pragma unroll
    for (int mt = 0; mt < 4; mt++) {
      u16x4_t t4;
#pragma unroll
      for (int r = 0; r < 4; r++) t4[r] = f2bf_t(a1c[mt][r]);
      *(u16x4_t*)&T1t[(nt * 16 + l15) * 72 + mt * 16 + quad * 4] = t4;
    }
  }

  // GEMM2: f2 = H*T1
  f32x4_t acc[4][4];
#pragma unroll
  for (int mt = 0; mt < 4; mt++)
#pragma unroll
    for (int nt = 0; nt < 4; nt++) acc[mt][nt] = (f32x4_t){0.f, 0.f, 0.f, 0.f};
#pragma unroll
  for (int kc = 0; kc < 2; kc++)
#pragma unroll
    for (int nt = 0; nt < 4; nt++) {
      bf16x8_t bfr = *(bf16x8_t*)&T1t[(nt * 16 + l15) * 72 + kc * 32 + quad * 8];
#pragma unroll
      for (int mt = 0; mt < 4; mt++)
        acc[mt][nt] = __builtin_amdgcn_mfma_f32_16x16x32_bf16(hf[kc][mt], bfr, acc[mt][nt], 0, 0, 0);
    }

  __syncthreads();                             // all T1t reads done before overlay
  // fill Fbuf[pos][c8]: this wave supplies c-lane = wave
#pragma unroll
  for (int mt = 0; mt < 4; mt++)
#pragma unroll
    for (int nt = 0; nt < 4; nt++)
#pragma unroll
      for (int r = 0; r < 4; r++) {
        int pos = (mt * 16 + quad * 4 + r) * 64 + nt * 16 + l15;  // kh*64+kw
        smem[pos * 8 + wave] = f2bf(acc[mt][nt][r]);
      }
  __syncthreads();
  // drain: coalesced u16x8 stores to F via Faddr
  size_t fbase = ((size_t)b * 32 + cg) * 4096;
#pragma unroll
  for (int i = 0; i < 8; i++) {
    int pos = i * 512 + tid;
    u16x8_t vch = *(u16x8_t*)&smem[pos * 8];
    *(u16x8_t*)(obuf + Faddr((fbase + pos) * 8)) = vch;
  }
}

// ---------------- k_gemm: Wcat @ F + soft-threshold (R7 pipeline) ----------------
// block = 256 thr = 4 waves; grid (32 n-tile, 4 m-tile, 32 b)
// LDS 64 KiB: A dbuf 2x[128 m][8 slot] (slot s holds gch=s^(m&7)); B dbuf
// 2x[8 cch][128 r] linear (global_load_lds dest). One barrier per ks.
__global__ __launch_bounds__(256) void k_gemm(const float* __restrict__ Wf,
                                              const float* __restrict__ vv,
                                              const float* __restrict__ TT,
                                              unsigned short* __restrict__ obuf) {
  __shared__ unsigned short smem2[32768];      // 64 KiB; epilogue overlays [0..8704)
  int tid = threadIdx.x;
  int lane = tid & 63, wave = tid >> 6;
  int quad = lane >> 4, l15 = lane & 15;
  int wm = wave & 1, wn = wave >> 1;
  int n0 = blockIdx.x * 128;                   // pos tile
  int m0 = blockIdx.y * 128;                   // Wcat row tile (m=2o+p)
  int b  = blockIdx.z;

  f32x4_t acc[4][4];
#pragma unroll
  for (int mt = 0; mt < 4; mt++)
#pragma unroll
    for (int nt = 0; nt < 4; nt++) acc[mt][nt] = (f32x4_t){0.f, 0.f, 0.f, 0.f};

  // ---- staging helpers ----
  auto issueB = [&](int ks, int buf) {         // 4x global_load_lds dwordx4, linear dest
    unsigned short* Bl = smem2 + 16384 + buf * 8192;
#pragma unroll
    for (int i = 0; i < 4; i++) {
      int idx = i * 256 + tid;
      int r = idx & 127, cch = idx >> 7;
      size_t f = (((size_t)b * 32 + ks * 8 + cch) * 4096 + n0 + r) * 8;
      const unsigned short* src = obuf + Faddr(f);
      __builtin_amdgcn_global_load_lds(
          (const __attribute__((address_space(1))) void*)src,
          (__attribute__((address_space(3))) void*)(Bl + idx * 8), 16, 0, 0);
    }
  };
  auto fetchA = [&](int ks, f32x4_t (&ar)[4][2]) {  // gch-swizzled coalesced fetch
    int k0 = ks * 64;
#pragma unroll
    for (int i = 0; i < 4; i++) {
      int idx = i * 256 + tid;
      int r = idx >> 3, cch = idx & 7;
      int gch = cch ^ (r & 7);
      int m = m0 + r;
      const float* wp = Wf + ((m & 1) << 16) + ((m >> 1) << 8) + k0 + gch * 8;
      ar[i][0] = *(const f32x4_t*)wp;
      ar[i][1] = *(const f32x4_t*)(wp + 4);
    }
  };
  auto writeA = [&](int buf, f32x4_t (&ar)[4][2]) { // convert + LINEAR store (0-conflict)
    unsigned short* Al = smem2 + buf * 8192;
#pragma unroll
    for (int i = 0; i < 4; i++) {
      int idx = i * 256 + tid;
      u16x8_t u;
#pragma unroll
      for (int j = 0; j < 4; j++) { u[j] = f2bf_t(ar[i][0][j]); u[4 + j] = f2bf_t(ar[i][1][j]); }
      *(u16x8_t*)&Al[idx * 8] = u;             // slot cch of row r holds gch=cch^(r&7)
    }
  };

  f32x4_t areg[4][2];
  issueB(0, 0);                                // B(0) DMA in flight during A(0) stage
  fetchA(0, areg);
  writeA(0, areg);
  __syncthreads();                             // drains vmcnt: B(0)+A(0) ready

  for (int ks = 0; ks < 4; ++ks) {
    int p = ks & 1;
    if (ks < 3) {                              // prefetch next tile before compute
      issueB(ks + 1, p ^ 1);
      fetchA(ks + 1, areg);
    }
    unsigned short* Al = smem2 + p * 8192;
    unsigned short* Bl = smem2 + 16384 + p * 8192;
#pragma unroll
    for (int kk = 0; kk < 2; ++kk) {
      bf16x8_t af[4], bfr[4];
#pragma unroll
      for (int mt = 0; mt < 4; mt++) {
        int row = wm * 64 + mt * 16 + l15;
        int s = (kk * 4 + quad) ^ (row & 7);   // swizzled A read (conflict-free, R5)
        af[mt] = *(const bf16x8_t*)&Al[row * 64 + s * 8];
      }
      int ch = kk * 4 + quad;
#pragma unroll
      for (int nt = 0; nt < 4; nt++)           // linear B read (conflict-free per R6 PMC)
        bfr[nt] = *(const bf16x8_t*)&Bl[ch * 1024 + (wn * 64 + nt * 16 + l15) * 8];
#pragma unroll
      for (int mt = 0; mt < 4; mt++)
#pragma unroll
        for (int nt = 0; nt < 4; nt++)
          acc[mt][nt] = __builtin_amdgcn_mfma_f32_16x16x32_bf16(af[mt], bfr[nt], acc[mt][nt], 0, 0, 0);
    }
    if (ks < 3) writeA(p ^ 1, areg);           // A(ks+1) into other buf (no race: all
                                               // waves read buf p this iteration)
    __syncthreads();                           // publish A(ks+1); land B(ks+1) DMA;
                                               // all reads of buf p retired
  }

  // epilogue: v-scale + soft-threshold both pods (reg parity = pod)
  // -> LDS tile [64 o][136 pos-stride] -> coalesced f6 row stores (slot-lo)
#pragma unroll
  for (int nt = 0; nt < 4; nt++) {
    int posl = wn * 64 + nt * 16 + l15;
    int pos = n0 + posl;
    float v0 = vv[pos], v1 = vv[4096 + pos];
    float t0 = TT[pos], t1 = TT[4096 + pos];
#pragma unroll
    for (int mt = 0; mt < 4; mt++)
#pragma unroll
      for (int rp = 0; rp < 2; rp++) {
        int ol = wm * 32 + mt * 8 + quad * 2 + rp;
        float z0 = acc[mt][nt][rp * 2 + 0] * v0;
        float z1 = acc[mt][nt][rp * 2 + 1] * v1;
        float s0 = copysignf(fmaxf(fabsf(z0) - t0, 0.f), z0);
        float s1 = copysignf(fmaxf(fabsf(z1) - t1, 0.f), z1);
        smem2[ol * 136 + posl] = f2bf(s0 + s1);
      }
  }
  __syncthreads();
  int o0 = m0 >> 1;
#pragma unroll
  for (int i = 0; i < 4; i++) {
    int ci = i * 256 + tid;                    // 1024 chunks = 64 rows x 16
    int row = ci >> 4, cc = ci & 15;
    u16x8_t vch = *(u16x8_t*)&smem2[row * 136 + cc * 8];
    size_t img = (size_t)b * 256 + o0 + row;
    *(u16x8_t*)(obuf + img * 8192 + n0 + cc * 8) = vch;
  }
}

// ---------------- k_inv: inverse 2D WHT via MFMA + /4096 + x (unchanged R5) ----------------
// block = 256 thr = 4 waves, wave -> image; grid 2048
__global__ __launch_bounds__(256) void k_inv(const float* __restrict__ x,
                                             unsigned short* __restrict__ obuf) {
  __shared__ unsigned short smem[18432];       // 4x per-wave [64][72] u16 tile
  int tid = threadIdx.x;
  int lane = tid & 63, wave = tid >> 6;
  int quad = lane >> 4, l15 = lane & 15;
  size_t img = (size_t)blockIdx.x * 4 + wave;
  unsigned short* T1t = smem + wave * 4608;

  // stage f6 coalesced (slot-lo u16x8) -> LDS tile [h][w] stride 72
#pragma unroll
  for (int l = 0; l < 8; l++) {
    int e = (l * 64 + lane) * 8;
    u16x8_t sv = *(const u16x8_t*)(obuf + img * 8192 + e);
    int row = e >> 6, col = e & 63;
    *(u16x8_t*)&T1t[row * 72 + col] = sv;
  }

  bf16x8_t hf[2][4];
#pragma unroll
  for (int kc = 0; kc < 2; kc++)
#pragma unroll
    for (int t = 0; t < 4; t++) {
      bf16x8_t h;
#pragma unroll
      for (int j = 0; j < 8; j++) {
        int k = kc * 32 + quad * 8 + j, n = t * 16 + l15;
        h[j] = (__builtin_popcount(k & n) & 1) ? (__bf16)-1.0f : (__bf16)1.0f;
      }
      hf[kc][t] = h;
    }

  // A-frags from LDS
  bf16x8_t fa[4][2];
#pragma unroll
  for (int mt = 0; mt < 4; mt++)
#pragma unroll
    for (int kc = 0; kc < 2; kc++)
      fa[mt][kc] = *(const bf16x8_t*)&T1t[(mt * 16 + l15) * 72 + kc * 32 + quad * 8];

  // GEMM1: U = f6*H, strip-mined; store transposed into T1t (reuse)
#pragma unroll
  for (int nt = 0; nt < 4; nt++) {
    f32x4_t a1c[4];
#pragma unroll
    for (int mt = 0; mt < 4; mt++) a1c[mt] = (f32x4_t){0.f, 0.f, 0.f, 0.f};
#pragma unroll
    for (int kc = 0; kc < 2; kc++)
#pragma unroll
      for (int mt = 0; mt < 4; mt++)
        a1c[mt] = __builtin_amdgcn_mfma_f32_16x16x32_bf16(fa[mt][kc], hf[kc][nt], a1c[mt], 0, 0, 0);
#pragma unroll
    for (int mt = 0; mt < 4; mt++) {
      u16x4_t t4;
#pragma unroll
      for (int r = 0; r < 4; r++) t4[r] = f2bf_t(a1c[mt][r]);
      *(u16x4_t*)&T1t[(nt * 16 + l15) * 72 + mt * 16 + quad * 4] = t4;
    }
  }

  // GEMM2: V = H*U
  f32x4_t acc[4][4];
#pragma unroll
  for (int mt = 0; mt < 4; mt++)
#pragma unroll
    for (int nt = 0; nt < 4; nt++) acc[mt][nt] = (f32x4_t){0.f, 0.f, 0.f, 0.f};
#pragma unroll
  for (int kc = 0; kc < 2; kc++)
#pragma unroll
    for (int nt = 0; nt < 4; nt++) {
      bf16x8_t bfr = *(bf16x8_t*)&T1t[(nt * 16 + l15) * 72 + kc * 32 + quad * 8];
#pragma unroll
      for (int mt = 0; mt < 4; mt++)
        acc[mt][nt] = __builtin_amdgcn_mfma_f32_16x16x32_bf16(hf[kc][mt], bfr, acc[mt][nt], 0, 0, 0);
    }

  // acc -> LDS tile [hh][ww] as bf16*(1/4096) (scalar u16 writes, 2-way free)
  const float sc = 1.0f / 4096.0f;
#pragma unroll
  for (int mt = 0; mt < 4; mt++)
#pragma unroll
    for (int nt = 0; nt < 4; nt++)
#pragma unroll
      for (int r = 0; r < 4; r++)
        T1t[(mt * 16 + quad * 4 + r) * 72 + nt * 16 + l15] = f2bf(acc[mt][nt][r] * sc);

  // drain: coalesced — LDS row chunks + x residual -> f32 out (in-place slot)
  float* outf = (float*)obuf;
  const float* xim = x + img * 4096;
#pragma unroll
  for (int l = 0; l < 8; l++) {
    int e = (l * 64 + lane) * 8;
    int row = e >> 6, col = e & 63;
    u16x8_t tv = *(u16x8_t*)&T1t[row * 72 + col];
    f32x4_t x0 = *(const f32x4_t*)(xim + e);
    f32x4_t x1 = *(const f32x4_t*)(xim + e + 4);
    f32x4_t o0, o1;
#pragma unroll
    for (int j = 0; j < 4; j++) { o0[j] = bf2f(tv[j]) + x0[j]; o1[j] = bf2f(tv[4 + j]) + x1[j]; }
    *(f32x4_t*)(outf + img * 4096 + e) = o0;
    *(f32x4_t*)(outf + img * 4096 + e + 4) = o1;
  }
}

extern "C" void kernel_launch(void* const* d_in, const int* in_sizes, int n_in,
                              void* d_out, int out_size, void* d_ws, size_t ws_size,
                              hipStream_t stream) {
  const float* x = (const float*)d_in[0];      // (32,256,64,64) f32
  const float* v = (const float*)d_in[1];      // (2,64,64) f32
  const float* W = (const float*)d_in[2];      // (2,256,256) f32
  const float* T = (const float*)d_in[3];      // (2,64,64) f32
  unsigned short* obuf = (unsigned short*)d_out;
  (void)d_ws; (void)ws_size; (void)in_sizes; (void)n_in; (void)out_size;

  k_fwd<<<dim3(32, 32), 512, 0, stream>>>(x, obuf);
  k_gemm<<<dim3(32, 4, 32), 256, 0, stream>>>(W, v, T, obuf);
  k_inv<<<2048, 256, 0, stream>>>(x, obuf);
}